// Round 3
// baseline (564.516 us; speedup 1.0000x reference)
//
#include <hip/hip_runtime.h>

typedef float floatx4 __attribute__((ext_vector_type(4)));
typedef int   intx4   __attribute__((ext_vector_type(4)));
typedef int   intx8   __attribute__((ext_vector_type(8)));

#define NC      100000
#define EMBD    512
#define BATCH   512
#define BN      64
#define NCH     1563        // ceil(100000/64)
#define NGB     196         // ceil(1563/8) groups of 8 bn per gblk

#define COS_M   0.8775825618903728f
#define SIN_M   0.479425538604203f
#define THRESH  (-0.8775825618903728f)
#define MM_C    0.2397127693021015f

// pack 8 floats -> 8 fp8 e4m3 bytes (two dwords)
__device__ __forceinline__ uint2 pack8_fp8(float4 a, float4 b) {
  int lo = 0, hi = 0;
  lo = __builtin_amdgcn_cvt_pk_fp8_f32(a.x, a.y, lo, false);
  lo = __builtin_amdgcn_cvt_pk_fp8_f32(a.z, a.w, lo, true);
  hi = __builtin_amdgcn_cvt_pk_fp8_f32(b.x, b.y, hi, false);
  hi = __builtin_amdgcn_cvt_pk_fp8_f32(b.z, b.w, hi, true);
  return make_uint2((unsigned)lo, (unsigned)hi);
}

// ---------------------------------------------------------------- prep_small
// Fuses: int64-label detect, label decode, emb->fp8 (normalized iff margin),
// exact fp32 target logit + arcface margin, out[0]=0 init.
__global__ __launch_bounds__(256) void prep_small_k(
    const float* __restrict__ emb, const float* __restrict__ weight,
    const float* __restrict__ fcw, const int* __restrict__ labels,
    const int* __restrict__ epoch, unsigned char* __restrict__ Aq,
    float* __restrict__ tsc, int* __restrict__ lab32,
    float* __restrict__ out) {
  const bool mm = (*epoch > 30);
  const int tid = threadIdx.x;
  const int pred = (labels[2 * tid + 1] != 0) ? 1 : 0;
  const bool is64 = (__syncthreads_or(pred) == 0);

  const int w = tid >> 6, lane = tid & 63;
  const int row = blockIdx.x * 4 + w;            // 0..511
  const int lab = is64 ? labels[2 * row] : labels[row];
  const float* W = mm ? weight : fcw;

  const float* er = emb + (size_t)row * EMBD + lane * 8;
  const float* wr = W + (size_t)lab * EMBD + lane * 8;
  float4 e0 = *(const float4*)er,  e1 = *(const float4*)(er + 4);
  float4 w0 = *(const float4*)wr,  w1 = *(const float4*)(wr + 4);
  float dot = e0.x*w0.x + e0.y*w0.y + e0.z*w0.z + e0.w*w0.w
            + e1.x*w1.x + e1.y*w1.y + e1.z*w1.z + e1.w*w1.w;
  float ssa = e0.x*e0.x + e0.y*e0.y + e0.z*e0.z + e0.w*e0.w
            + e1.x*e1.x + e1.y*e1.y + e1.z*e1.z + e1.w*e1.w;
  float ssw = w0.x*w0.x + w0.y*w0.y + w0.z*w0.z + w0.w*w0.w
            + w1.x*w1.x + w1.y*w1.y + w1.z*w1.z + w1.w*w1.w;
  #pragma unroll
  for (int off = 32; off; off >>= 1) {
    dot += __shfl_xor(dot, off, 64);
    ssa += __shfl_xor(ssa, off, 64);
    ssw += __shfl_xor(ssw, off, 64);
  }
  const float inva = mm ? (1.0f / fmaxf(sqrtf(ssa), 1e-12f)) : 1.0f;
  float4 q0 = make_float4(e0.x*inva, e0.y*inva, e0.z*inva, e0.w*inva);
  float4 q1 = make_float4(e1.x*inva, e1.y*inva, e1.z*inva, e1.w*inva);
  *(uint2*)(Aq + (size_t)row * EMBD + lane * 8) = pack8_fp8(q0, q1);

  if (lane == 0) {
    lab32[row] = lab;
    float tv;
    if (mm) {
      float cosv = dot / (fmaxf(sqrtf(ssa), 1e-12f) * fmaxf(sqrtf(ssw), 1e-12f));
      float sinv = sqrtf(fmaxf(1.0f - cosv * cosv, 0.0f));
      float wmarg = cosv * COS_M - sinv * SIN_M;
      float nt = (cosv > THRESH) ? wmarg : (cosv - MM_C);
      tv = 64.0f * nt;
    } else {
      tv = dot;
    }
    tsc[row] = tv;
  }
  if (blockIdx.x == 0 && tid == 0) out[0] = 0.0f;
}

// ---------------------------------------------------------------- fused pack + fp8 GEMM + chunk-softmax
// Block = 128 A-rows x 64 B-cols. The block packs its OWN B-chunk (W fp32 ->
// normalized fp8) straight into LDS (one wave-row = 64 lanes x 8 floats = EMBD),
// eliminating the prep_w kernel and the Wq global round-trip. The 4 bm-blocks
// of one bn are dispatch-adjacent (same XCD) so the 3 redundant W reads are
// L2 hits; first-touch HBM for W is 205 MB total, overlapped with MFMA.
// A-fragments are loaded directly into registers from the L2-resident Aq
// (256 KB), so the K-loop has NO barriers.
// Bs swizzle: within each 128B k-slice, 16B chunk j of local row r stored at
// chunk j^(r&7); write and read sides use the same involution, and A/B consume
// identical k-byte order, so any HW k-permutation cancels in the dot product.
__global__ __launch_bounds__(256, 2) void gemm_fused_k(
    const unsigned char* __restrict__ Aq, const float* __restrict__ weight,
    const float* __restrict__ fcw, const float* __restrict__ tsc,
    const int* __restrict__ lab32, const int* __restrict__ epoch,
    float2* __restrict__ partials) {
  const int t = blockIdx.x & 31, gblk = blockIdx.x >> 5;
  const int bn = gblk * 8 + (t & 7);     // XCD swizzle: 4 bm's of one bn land
  const int bm = t >> 3;                 // 8 dispatch-ids apart (same XCD)
  if (bn >= NCH) return;

  const bool mm = (*epoch > 30);
  const float scale = mm ? 64.0f : 1.0f;
  const float* __restrict__ Wp = mm ? weight : fcw;

  __shared__ unsigned char Bs[BN * EMBD];   // 32 KB, full-K packed B chunk
  __shared__ float tscS[128];
  __shared__ int   labS[128];

  const int tid  = threadIdx.x;
  const int lane = tid & 63;
  const int w    = tid >> 6;
  const int m0   = bm * 128;
  const int n0   = bn * BN;

  if (tid < 128) { tscS[tid] = tsc[m0 + tid]; labS[tid] = lab32[m0 + tid]; }

  // ---- pack phase: wave w packs local rows [w*16, w*16+16)
  #pragma unroll 4
  for (int rr = 0; rr < 16; ++rr) {
    const int r    = w * 16 + rr;        // local row 0..63
    const int grow = n0 + r;
    uint2 pq = make_uint2(0u, 0u);
    if (grow < NC) {                     // wave-uniform branch
      const float* src = Wp + (size_t)grow * EMBD + lane * 8;
      float4 a = *(const float4*)src;
      float4 b = *(const float4*)(src + 4);
      float ss = a.x*a.x + a.y*a.y + a.z*a.z + a.w*a.w
               + b.x*b.x + b.y*b.y + b.z*b.z + b.w*b.w;
      #pragma unroll
      for (int off = 32; off; off >>= 1) ss += __shfl_xor(ss, off, 64);
      const float inv = mm ? (1.0f / fmaxf(sqrtf(ss), 1e-12f)) : 1.0f;
      float4 qa = make_float4(a.x*inv, a.y*inv, a.z*inv, a.w*inv);
      float4 qb = make_float4(b.x*inv, b.y*inv, b.z*inv, b.w*inv);
      pq = pack8_fp8(qa, qb);
    }
    // lane's 8 logical bytes [lane*8, lane*8+8) of row r, swizzled:
    // slice = lane>>4 (128B), in-slice chunk = (lane>>1)&7, half = lane&1
    const int addr = r * EMBD + ((lane >> 4) << 7)
                   + (((((lane >> 1) & 7) ^ (r & 7))) << 4) + ((lane & 1) << 3);
    *(uint2*)&Bs[addr] = pq;
  }
  __syncthreads();

  // ---- barrier-free K-loop
  const int rsel = lane & 15;
  const int g32  = (lane >> 4) * 32;                 // lane-group k-byte offset
  const int c0   = ((((lane >> 4) * 2)     ^ (rsel & 7)) << 4);
  const int c1   = (((((lane >> 4) * 2)+1) ^ (rsel & 7)) << 4);

  floatx4 acc[2][4];
  #pragma unroll
  for (int i = 0; i < 2; i++)
    #pragma unroll
    for (int j = 0; j < 4; j++) acc[i][j] = (floatx4){0.f, 0.f, 0.f, 0.f};

  #pragma unroll
  for (int kt = 0; kt < 4; ++kt) {
    intx8 af[2];
    #pragma unroll
    for (int mi = 0; mi < 2; mi++) {
      const unsigned char* ap =
          Aq + (size_t)(m0 + w * 32 + mi * 16 + rsel) * EMBD + kt * 128 + g32;
      intx4 alo = *(const intx4*)ap;          // two explicit 16B loads ->
      intx4 ahi = *(const intx4*)(ap + 16);   // guaranteed dwordx4 codegen
      af[mi] = __builtin_shufflevector(alo, ahi, 0, 1, 2, 3, 4, 5, 6, 7);
    }
    intx8 bv[4];
    #pragma unroll
    for (int ni = 0; ni < 4; ni++) {
      const int base = (ni * 16 + rsel) * EMBD + kt * 128;
      intx4 lo = *(const intx4*)&Bs[base + c0];
      intx4 hi = *(const intx4*)&Bs[base + c1];
      bv[ni] = __builtin_shufflevector(lo, hi, 0, 1, 2, 3, 4, 5, 6, 7);
    }
    #pragma unroll
    for (int mi = 0; mi < 2; mi++)
      #pragma unroll
      for (int ni = 0; ni < 4; ni++)
        acc[mi][ni] = __builtin_amdgcn_mfma_scale_f32_16x16x128_f8f6f4(
            af[mi], bv[ni], acc[mi][ni], 0, 0,
            0, 0x7f7f7f7f, 0, 0x7f7f7f7f);
  }

  // epilogue: C/D layout col = lane&15, row = (lane>>4)*4 + r
  const int colq = lane & 15;
  #pragma unroll
  for (int mi = 0; mi < 2; mi++) {
    #pragma unroll
    for (int r = 0; r < 4; r++) {
      const int rl = w * 32 + mi * 16 + (lane >> 4) * 4 + r;
      const int lab = labS[rl];
      const float tv = tscS[rl];
      float v[4];
      #pragma unroll
      for (int ni = 0; ni < 4; ni++) {
        const int cg = n0 + ni * 16 + colq;
        float x = acc[mi][ni][r] * scale;
        if (cg >= NC) x = -1e30f;
        else if (cg == lab) x = tv;
        v[ni] = x;
      }
      float mx = v[0];
      #pragma unroll
      for (int ni = 1; ni < 4; ni++) mx = fmaxf(mx, v[ni]);
      #pragma unroll
      for (int off = 1; off < 16; off <<= 1) mx = fmaxf(mx, __shfl_xor(mx, off, 64));
      float s = 0.0f;
      #pragma unroll
      for (int ni = 0; ni < 4; ni++) s += __expf(v[ni] - mx);
      #pragma unroll
      for (int off = 1; off < 16; off <<= 1) s += __shfl_xor(s, off, 64);
      if (colq == 0)
        partials[(size_t)(m0 + rl) * NCH + bn] = make_float2(mx, s);
    }
  }
}

// ---------------------------------------------------------------- per-row logsumexp + atomic mean
__global__ __launch_bounds__(256) void rowmerge_k(
    const float2* __restrict__ partials, const float* __restrict__ tsc,
    float* __restrict__ out) {
  const int row = blockIdx.x;    // 512
  const int tid = threadIdx.x;   // 256
  float M = -1e30f, S = 0.0f;
  for (int j = tid; j < NCH; j += 256) {
    const float2 p = partials[(size_t)row * NCH + j];
    if (p.x > M) { S = S * __expf(M - p.x) + p.y; M = p.x; }
    else         { S += p.y * __expf(p.x - M); }
  }
  __shared__ float sm[256], sv[256];
  sm[tid] = M; sv[tid] = S;
  __syncthreads();
  for (int st = 128; st > 0; st >>= 1) {
    if (tid < st) {
      const float m2 = sm[tid + st], s2 = sv[tid + st];
      const float m1 = sm[tid],      s1 = sv[tid];
      const float Mn = fmaxf(m1, m2);
      sv[tid] = s1 * __expf(m1 - Mn) + s2 * __expf(m2 - Mn);
      sm[tid] = Mn;
    }
    __syncthreads();
  }
  if (tid == 0) {
    const float loss = (sm[0] + __logf(sv[0])) - tsc[row];
    atomicAdd(out, loss * (1.0f / 512.0f));
  }
}

// ----------------------------------------------------------------
extern "C" void kernel_launch(void* const* d_in, const int* in_sizes, int n_in,
                              void* d_out, int out_size, void* d_ws, size_t ws_size,
                              hipStream_t stream) {
  const float* emb    = (const float*)d_in[0];
  const float* weight = (const float*)d_in[1];
  const float* fcw    = (const float*)d_in[2];
  const int*   labels = (const int*)d_in[3];
  const int*   epoch  = (const int*)d_in[4];
  float* out = (float*)d_out;

  char* ws = (char*)d_ws;
  size_t off = 0;
  unsigned char* Aq = (unsigned char*)(ws + off); off += (size_t)BATCH * EMBD;   // 256 KB
  float* tsc       = (float*)(ws + off); off += BATCH * 4;
  int* lab32       = (int*)(ws + off);   off += BATCH * 4;
  float2* partials = (float2*)(ws + off); off += (size_t)BATCH * NCH * 8;        // ~6.4 MB

  prep_small_k<<<BATCH / 4, 256, 0, stream>>>(emb, weight, fcw, labels, epoch,
                                              Aq, tsc, lab32, out);
  gemm_fused_k<<<NGB * 32, 256, 0, stream>>>(Aq, weight, fcw, tsc, lab32, epoch,
                                             partials);
  rowmerge_k<<<BATCH, 256, 0, stream>>>(partials, tsc, out);
}

// Round 5
// 507.934 us; speedup vs baseline: 1.1114x; 1.1114x over previous
//
#include <hip/hip_runtime.h>

typedef float floatx4 __attribute__((ext_vector_type(4)));
typedef int   intx4   __attribute__((ext_vector_type(4)));
typedef int   intx8   __attribute__((ext_vector_type(8)));

#define NC      100000
#define EMBD    512
#define BATCH   512
#define BN      64
#define BM      256
#define NCH     1563        // ceil(100000/64)
#define NGB     196         // ceil(1563/8) groups; 16 blocks per group (8 bn x 2 bm)

#define WSCALE      1024.0f     // exact pow2 pre-quantization scale for W
#define INV_WSCALE  (1.0f / 1024.0f)

#define COS_M   0.8775825618903728f
#define SIN_M   0.479425538604203f
#define THRESH  (-0.8775825618903728f)
#define MM_C    0.2397127693021015f

// pack 8 floats -> 8 fp8 e4m3 bytes (two dwords)
__device__ __forceinline__ uint2 pack8_fp8(float4 a, float4 b) {
  int lo = 0, hi = 0;
  lo = __builtin_amdgcn_cvt_pk_fp8_f32(a.x, a.y, lo, false);
  lo = __builtin_amdgcn_cvt_pk_fp8_f32(a.z, a.w, lo, true);
  hi = __builtin_amdgcn_cvt_pk_fp8_f32(b.x, b.y, hi, false);
  hi = __builtin_amdgcn_cvt_pk_fp8_f32(b.z, b.w, hi, true);
  return make_uint2((unsigned)lo, (unsigned)hi);
}

// ---------------------------------------------------------------- prep_small
// Fuses: int64-label detect, label decode, emb->fp8 (normalized iff margin),
// exact fp32 target logit + arcface margin, out[0]=0 init.
__global__ __launch_bounds__(256) void prep_small_k(
    const float* __restrict__ emb, const float* __restrict__ weight,
    const float* __restrict__ fcw, const int* __restrict__ labels,
    const int* __restrict__ epoch, unsigned char* __restrict__ Aq,
    float* __restrict__ tsc, int* __restrict__ lab32,
    float* __restrict__ out) {
  const bool mm = (*epoch > 30);
  const int tid = threadIdx.x;
  const int pred = (labels[2 * tid + 1] != 0) ? 1 : 0;
  const bool is64 = (__syncthreads_or(pred) == 0);

  const int w = tid >> 6, lane = tid & 63;
  const int row = blockIdx.x * 4 + w;            // 0..511
  const int lab = is64 ? labels[2 * row] : labels[row];
  const float* W = mm ? weight : fcw;

  const float* er = emb + (size_t)row * EMBD + lane * 8;
  const float* wr = W + (size_t)lab * EMBD + lane * 8;
  float4 e0 = *(const float4*)er,  e1 = *(const float4*)(er + 4);
  float4 w0 = *(const float4*)wr,  w1 = *(const float4*)(wr + 4);
  float dot = e0.x*w0.x + e0.y*w0.y + e0.z*w0.z + e0.w*w0.w
            + e1.x*w1.x + e1.y*w1.y + e1.z*w1.z + e1.w*w1.w;
  float ssa = e0.x*e0.x + e0.y*e0.y + e0.z*e0.z + e0.w*e0.w
            + e1.x*e1.x + e1.y*e1.y + e1.z*e1.z + e1.w*e1.w;
  float ssw = w0.x*w0.x + w0.y*w0.y + w0.z*w0.z + w0.w*w0.w
            + w1.x*w1.x + w1.y*w1.y + w1.z*w1.z + w1.w*w1.w;
  #pragma unroll
  for (int off = 32; off; off >>= 1) {
    dot += __shfl_xor(dot, off, 64);
    ssa += __shfl_xor(ssa, off, 64);
    ssw += __shfl_xor(ssw, off, 64);
  }
  const float inva = mm ? (1.0f / fmaxf(sqrtf(ssa), 1e-12f)) : 1.0f;
  float4 q0 = make_float4(e0.x*inva, e0.y*inva, e0.z*inva, e0.w*inva);
  float4 q1 = make_float4(e1.x*inva, e1.y*inva, e1.z*inva, e1.w*inva);
  *(uint2*)(Aq + (size_t)row * EMBD + lane * 8) = pack8_fp8(q0, q1);

  if (lane == 0) {
    lab32[row] = lab;
    float tv;
    if (mm) {
      float cosv = dot / (fmaxf(sqrtf(ssa), 1e-12f) * fmaxf(sqrtf(ssw), 1e-12f));
      float sinv = sqrtf(fmaxf(1.0f - cosv * cosv, 0.0f));
      float wmarg = cosv * COS_M - sinv * SIN_M;
      float nt = (cosv > THRESH) ? wmarg : (cosv - MM_C);
      tv = 64.0f * nt;
    } else {
      tv = dot;
    }
    tsc[row] = tv;
  }
  if (blockIdx.x == 0 && tid == 0) out[0] = 0.0f;
}

// ---------------------------------------------------------------- fused pack + fp8 GEMM + chunk-softmax
// Block = 256 A-rows x 64 B-cols. Pack phase: W rows are quantized with a
// CONSTANT pow2 scale (x1024) so the fp8 pack has NO dependency on the row
// norm -> the 32 global b128 loads stream without a cross-lane reduce in the
// chain. Per-lane ssq partials are kept in registers and reduced AFTER the
// store loop; 1/(1024*|w|) lands in invnS[] and is applied per-column in the
// epilogue (target logit stays exact from prep_small). BM=256 halves the
// pack duplication vs BM=128 (each W chunk packed by 2 bm-blocks, not 4).
// K-loop is barrier-free: A fragments come straight from L2-resident Aq.
// Bs swizzle: 16B chunk j of local row r stored at chunk j^(r&7) within each
// 128B k-slice; read side applies the same involution; A/B consume identical
// k-byte order so any HW k-permutation cancels.
__global__ __launch_bounds__(256, 2) void gemm_fused_k(
    const unsigned char* __restrict__ Aq, const float* __restrict__ weight,
    const float* __restrict__ fcw, const float* __restrict__ tsc,
    const int* __restrict__ lab32, const int* __restrict__ epoch,
    float2* __restrict__ partials) {
  const int t = blockIdx.x & 15, gblk = blockIdx.x >> 4;
  const int bn = gblk * 8 + (t & 7);     // XCD swizzle: the 2 bm's of one bn
  const int bm = t >> 3;                 // are 8 dispatch-ids apart (same XCD)
  if (bn >= NCH) return;

  const bool mm = (*epoch > 30);
  const float scale = mm ? 64.0f : 1.0f;
  const float* __restrict__ Wp = mm ? weight : fcw;

  __shared__ unsigned char Bs[BN * EMBD];   // 32 KB, full-K packed B chunk
  __shared__ float tscS[BM];
  __shared__ int   labS[BM];
  __shared__ float invnS[BN];

  const int tid  = threadIdx.x;
  const int lane = tid & 63;
  const int w    = tid >> 6;
  const int m0   = bm * BM;
  const int n0   = bn * BN;

  tscS[tid] = tsc[m0 + tid];
  labS[tid] = lab32[m0 + tid];

  // ---- pack phase: wave w packs local rows [w*16, w*16+16), no cross-lane
  // dependency inside the loop -> loads pipeline freely.
  float ssp[16];
  #pragma unroll
  for (int rr = 0; rr < 16; ++rr) {
    const int r    = w * 16 + rr;        // local row 0..63
    const int grow = n0 + r;
    uint2 pq = make_uint2(0u, 0u);
    float ssl = 0.0f;
    if (grow < NC) {                     // wave-uniform branch
      const float* src = Wp + (size_t)grow * EMBD + lane * 8;
      float4 a = *(const float4*)src;
      float4 b = *(const float4*)(src + 4);
      ssl = a.x*a.x + a.y*a.y + a.z*a.z + a.w*a.w
          + b.x*b.x + b.y*b.y + b.z*b.z + b.w*b.w;
      float4 qa = make_float4(a.x*WSCALE, a.y*WSCALE, a.z*WSCALE, a.w*WSCALE);
      float4 qb = make_float4(b.x*WSCALE, b.y*WSCALE, b.z*WSCALE, b.w*WSCALE);
      pq = pack8_fp8(qa, qb);
    }
    ssp[rr] = ssl;
    // lane's 8 logical bytes of row r, swizzled:
    const int addr = r * EMBD + ((lane >> 4) << 7)
                   + (((((lane >> 1) & 7) ^ (r & 7))) << 4) + ((lane & 1) << 3);
    *(uint2*)&Bs[addr] = pq;
  }

  // deferred cross-lane reductions (independent butterfly chains)
  #pragma unroll
  for (int rr = 0; rr < 16; ++rr) {
    float s = ssp[rr];
    #pragma unroll
    for (int off = 32; off; off >>= 1) s += __shfl_xor(s, off, 64);
    ssp[rr] = s;
  }
  if (lane == 0) {
    #pragma unroll
    for (int rr = 0; rr < 16; ++rr) {
      invnS[w * 16 + rr] =
          mm ? (INV_WSCALE / fmaxf(sqrtf(ssp[rr]), 1e-12f)) : INV_WSCALE;
    }
  }
  __syncthreads();

  // ---- barrier-free K-loop
  const int rsel = lane & 15;
  const int g32  = (lane >> 4) * 32;                 // lane-group k-byte offset
  const int c0   = ((((lane >> 4) * 2)     ^ (rsel & 7)) << 4);
  const int c1   = (((((lane >> 4) * 2)+1) ^ (rsel & 7)) << 4);

  floatx4 acc[4][4];
  #pragma unroll
  for (int i = 0; i < 4; i++)
    #pragma unroll
    for (int j = 0; j < 4; j++) acc[i][j] = (floatx4){0.f, 0.f, 0.f, 0.f};

  #pragma unroll
  for (int kt = 0; kt < 4; ++kt) {
    intx8 af[4];
    #pragma unroll
    for (int mi = 0; mi < 4; mi++) {
      const unsigned char* ap =
          Aq + (size_t)(m0 + w * 64 + mi * 16 + rsel) * EMBD + kt * 128 + g32;
      intx4 alo = *(const intx4*)ap;
      intx4 ahi = *(const intx4*)(ap + 16);
      af[mi] = __builtin_shufflevector(alo, ahi, 0, 1, 2, 3, 4, 5, 6, 7);
    }
    intx8 bv[4];
    #pragma unroll
    for (int ni = 0; ni < 4; ni++) {
      const int base = (ni * 16 + rsel) * EMBD + kt * 128;
      intx4 lo = *(const intx4*)&Bs[base + c0];
      intx4 hi = *(const intx4*)&Bs[base + c1];
      bv[ni] = __builtin_shufflevector(lo, hi, 0, 1, 2, 3, 4, 5, 6, 7);
    }
    #pragma unroll
    for (int mi = 0; mi < 4; mi++)
      #pragma unroll
      for (int ni = 0; ni < 4; ni++)
        acc[mi][ni] = __builtin_amdgcn_mfma_scale_f32_16x16x128_f8f6f4(
            af[mi], bv[ni], acc[mi][ni], 0, 0,
            0, 0x7f7f7f7f, 0, 0x7f7f7f7f);
  }

  // epilogue: C/D layout col = lane&15, row = (lane>>4)*4 + r
  const int colq = lane & 15;
  #pragma unroll
  for (int mi = 0; mi < 4; mi++) {
    #pragma unroll
    for (int r = 0; r < 4; r++) {
      const int rl = w * 64 + mi * 16 + (lane >> 4) * 4 + r;
      const int lab = labS[rl];
      const float tv = tscS[rl];
      float v[4];
      #pragma unroll
      for (int ni = 0; ni < 4; ni++) {
        const int cg = n0 + ni * 16 + colq;
        float x = acc[mi][ni][r] * scale * invnS[ni * 16 + colq];
        if (cg >= NC) x = -1e30f;
        else if (cg == lab) x = tv;
        v[ni] = x;
      }
      float mx = v[0];
      #pragma unroll
      for (int ni = 1; ni < 4; ni++) mx = fmaxf(mx, v[ni]);
      #pragma unroll
      for (int off = 1; off < 16; off <<= 1) mx = fmaxf(mx, __shfl_xor(mx, off, 64));
      float s = 0.0f;
      #pragma unroll
      for (int ni = 0; ni < 4; ni++) s += __expf(v[ni] - mx);
      #pragma unroll
      for (int off = 1; off < 16; off <<= 1) s += __shfl_xor(s, off, 64);
      if (colq == 0)
        partials[(size_t)(m0 + rl) * NCH + bn] = make_float2(mx, s);
    }
  }
}

// ---------------------------------------------------------------- per-row logsumexp + atomic mean
__global__ __launch_bounds__(256) void rowmerge_k(
    const float2* __restrict__ partials, const float* __restrict__ tsc,
    float* __restrict__ out) {
  const int row = blockIdx.x;    // 512
  const int tid = threadIdx.x;   // 256
  float M = -1e30f, S = 0.0f;
  for (int j = tid; j < NCH; j += 256) {
    const float2 p = partials[(size_t)row * NCH + j];
    if (p.x > M) { S = S * __expf(M - p.x) + p.y; M = p.x; }
    else         { S += p.y * __expf(p.x - M); }
  }
  __shared__ float sm[256], sv[256];
  sm[tid] = M; sv[tid] = S;
  __syncthreads();
  for (int st = 128; st > 0; st >>= 1) {
    if (tid < st) {
      const float m2 = sm[tid + st], s2 = sv[tid + st];
      const float m1 = sm[tid],      s1 = sv[tid];
      const float Mn = fmaxf(m1, m2);
      sv[tid] = s1 * __expf(m1 - Mn) + s2 * __expf(m2 - Mn);
      sm[tid] = Mn;
    }
    __syncthreads();
  }
  if (tid == 0) {
    const float loss = (sm[0] + __logf(sv[0])) - tsc[row];
    atomicAdd(out, loss * (1.0f / 512.0f));
  }
}

// ----------------------------------------------------------------
extern "C" void kernel_launch(void* const* d_in, const int* in_sizes, int n_in,
                              void* d_out, int out_size, void* d_ws, size_t ws_size,
                              hipStream_t stream) {
  const float* emb    = (const float*)d_in[0];
  const float* weight = (const float*)d_in[1];
  const float* fcw    = (const float*)d_in[2];
  const int*   labels = (const int*)d_in[3];
  const int*   epoch  = (const int*)d_in[4];
  float* out = (float*)d_out;

  char* ws = (char*)d_ws;
  size_t off = 0;
  unsigned char* Aq = (unsigned char*)(ws + off); off += (size_t)BATCH * EMBD;   // 256 KB
  float* tsc       = (float*)(ws + off); off += BATCH * 4;
  int* lab32       = (int*)(ws + off);   off += BATCH * 4;
  float2* partials = (float2*)(ws + off); off += (size_t)BATCH * NCH * 8;        // ~6.4 MB

  prep_small_k<<<BATCH / 4, 256, 0, stream>>>(emb, weight, fcw, labels, epoch,
                                              Aq, tsc, lab32, out);
  gemm_fused_k<<<NGB * 16, 256, 0, stream>>>(Aq, weight, fcw, tsc, lab32, epoch,
                                             partials);
  rowmerge_k<<<BATCH, 256, 0, stream>>>(partials, tsc, out);
}